// Round 3
// baseline (259.772 us; speedup 1.0000x reference)
//
#include <hip/hip_runtime.h>

#define FRAME 160
#define ORDER 16
#define LPC_EPS 1e-8f
#define NF 32        // frames per block
#define BS 256       // threads per block (4 waves); 8 threads per frame
#define PPF 8        // threads (parts) per frame; 20 samples each
#define SEG 20       // samples per part
#define SX 164       // padded LDS row stride in floats (+4-float skew vs 160)
#define QPB (NF * FRAME / 4 / BS)  // 5 float4 iterations per thread stage-in/out

// One block = 32 frames end-to-end. LDS 20,992 B -> 7 blocks/CU (28 waves).
// stage-in (coalesced) -> autocorr (8-way split, shfl-xor reduce over 8 lanes)
// -> Levinson (redundant per 8-lane group, coeffs stay in registers)
// -> FIR in-place into LDS -> coalesced stage-out.
__global__ __launch_bounds__(BS, 7) void lpc_fused(const float* __restrict__ x,
                                                   float* __restrict__ out) {
    __shared__ float xs[NF * SX];  // 20,992 B

    const int t = threadIdx.x;
    const long long base = (long long)blockIdx.x * (NF * FRAME);

    // ---- stage in: 1280 consecutive float4, fully coalesced ----
#pragma unroll
    for (int it = 0; it < QPB; ++it) {
        int p = it * BS + t;              // quad index within block [0,1280)
        int f = p / 40;                   // 40 quads per frame
        int off = (p - f * 40) * 4;
        float4 v = *(const float4*)(x + base + 4 * p);
        *(float4*)(&xs[f * SX + off]) = v;
    }
    __syncthreads();

    const int fi = t >> 3;       // frame within block [0,32)
    const int part = t & 7;      // n-range: [20*part, 20*part+20)
    const int sbase = SEG * part;

    // ---- window w[j] = x[sbase + j], j in [0,36), zero-padded past frame end ----
    float w[SEG + ORDER];
#pragma unroll
    for (int m = 0; m < (SEG + ORDER) / 4; ++m) {
        int idx = sbase + 4 * m;
        float4 v = make_float4(0.f, 0.f, 0.f, 0.f);
        if (idx < FRAME) v = *(const float4*)(&xs[fi * SX + idx]);
        w[4 * m + 0] = v.x; w[4 * m + 1] = v.y;
        w[4 * m + 2] = v.z; w[4 * m + 3] = v.w;
    }

    // ---- partial autocorrelation over 20 samples, all 17 lags ----
    float r[ORDER + 1];
#pragma unroll
    for (int k = 0; k <= ORDER; ++k) r[k] = 0.f;
#pragma unroll
    for (int n = 0; n < SEG; ++n) {
#pragma unroll
        for (int k = 0; k <= ORDER; ++k) {
            r[k] = fmaf(w[n], w[n + k], r[k]);
        }
    }
    // 8-lane butterfly: every lane of the group gets full-frame r[k]
#pragma unroll
    for (int k = 0; k <= ORDER; ++k) {
        r[k] += __shfl_xor(r[k], 1);
        r[k] += __shfl_xor(r[k], 2);
        r[k] += __shfl_xor(r[k], 4);
    }

    // ---- Levinson-Durbin (redundant across the 8 group lanes; result in regs) ----
    float a[ORDER + 1];
    a[0] = 1.f;
#pragma unroll
    for (int j = 1; j <= ORDER; ++j) a[j] = 0.f;
    float e = (r[0] != 0.f) ? r[0] : LPC_EPS;  // e >= EPS > 0 afterwards
#pragma unroll
    for (int i = 1; i <= ORDER; ++i) {
        float acc = r[i];
#pragma unroll
        for (int j = 1; j < i; ++j) acc -= a[j] * r[i - j];
        float k = acc / e;
        float na[ORDER + 1];
#pragma unroll
        for (int j = 1; j < i; ++j) na[j] = a[j] - k * a[i - j];
#pragma unroll
        for (int j = 1; j < i; ++j) a[j] = na[j];
        a[i] = k;
        e = fmaxf(e * (1.f - k * k), LPC_EPS);
    }

    // ---- FIR look-back: pre[j] = x[sbase - 16 + j], zeros before frame start ----
    float pre[ORDER];
#pragma unroll
    for (int m = 0; m < ORDER / 4; ++m) {
        int idx = sbase - ORDER + 4 * m;
        float4 v = make_float4(0.f, 0.f, 0.f, 0.f);
        if (idx >= 0) v = *(const float4*)(&xs[fi * SX + idx]);
        pre[4 * m + 0] = v.x; pre[4 * m + 1] = v.y;
        pre[4 * m + 2] = v.z; pre[4 * m + 3] = v.w;
    }

    __syncthreads();  // ALL xs reads done before in-place overwrite

    // ---- FIR: res[sbase+n] = sum_k a[k] * x[sbase+n-k], written in place ----
#pragma unroll
    for (int m = 0; m < SEG / 4; ++m) {
        float o[4];
#pragma unroll
        for (int i = 0; i < 4; ++i) {
            int n = 4 * m + i;
            float s = 0.f;
#pragma unroll
            for (int k = 0; k <= ORDER; ++k) {
                int j = n - k;                       // compile-time
                float xv = (j >= 0) ? w[j] : pre[ORDER + j];
                s = fmaf(a[k], xv, s);
            }
            o[i] = s;
        }
        *(float4*)(&xs[fi * SX + sbase + 4 * m]) = make_float4(o[0], o[1], o[2], o[3]);
    }
    __syncthreads();

    // ---- stage out: fully coalesced ----
#pragma unroll
    for (int it = 0; it < QPB; ++it) {
        int p = it * BS + t;
        int f = p / 40;
        int off = (p - f * 40) * 4;
        float4 v = *(const float4*)(&xs[f * SX + off]);
        *(float4*)(out + base + 4 * p) = v;
    }
}

extern "C" void kernel_launch(void* const* d_in, const int* in_sizes, int n_in,
                              void* d_out, int out_size, void* d_ws, size_t ws_size,
                              hipStream_t stream) {
    const float* x = (const float*)d_in[0];
    float* out = (float*)d_out;
    int total = in_sizes[0];                 // 20,480,000 = 128,000 frames
    int n_frames = total / FRAME;
    int n_blocks = n_frames / NF;            // 4000 (exact for this problem shape)
    lpc_fused<<<n_blocks, BS, 0, stream>>>(x, out);
}

// Round 4
// 143.169 us; speedup vs baseline: 1.8144x; 1.8144x over previous
//
#include <hip/hip_runtime.h>

#define FRAME 160
#define ORDER 16
#define LPC_EPS 1e-8f
#define NF 32        // frames per block
#define BS 256       // threads per block (4 waves); 8 threads per frame
#define SEG 20       // samples per part (8 parts per frame)
#define SX 164       // padded LDS row stride in floats (+4-float skew vs 160)
#define QPB (NF * FRAME / 4 / BS)  // 5 float4 iterations per thread stage-in/out

// One block = 32 frames end-to-end. LDS 20,992 B (7 blocks/CU LDS-wise).
// launch_bounds(256,4): 128-VGPR cap -- compiler lands ~70, NO scratch spills
// (Round 3's (256,7) forced 36 VGPRs -> 480 MB of spill traffic, 3x slowdown).
__global__ __launch_bounds__(BS, 4) void lpc_fused(const float* __restrict__ x,
                                                   float* __restrict__ out) {
    __shared__ float xs[NF * SX];  // 20,992 B

    const int t = threadIdx.x;
    const long long base = (long long)blockIdx.x * (NF * FRAME);

    // ---- stage in: 1280 consecutive float4, fully coalesced ----
#pragma unroll
    for (int it = 0; it < QPB; ++it) {
        int p = it * BS + t;              // quad index within block [0,1280)
        int f = p / 40;                   // 40 quads per frame
        int off = (p - f * 40) * 4;
        float4 v = *(const float4*)(x + base + 4 * p);
        *(float4*)(&xs[f * SX + off]) = v;
    }
    __syncthreads();

    const int fi = t >> 3;       // frame within block [0,32)
    const int part = t & 7;      // n-range: [20*part, 20*part+20)
    const int sbase = SEG * part;

    // ---- window w[j] = x[sbase + j], j in [0,36), zero-padded past frame end ----
    float w[SEG + ORDER];
#pragma unroll
    for (int m = 0; m < (SEG + ORDER) / 4; ++m) {
        int idx = sbase + 4 * m;
        float4 v = make_float4(0.f, 0.f, 0.f, 0.f);
        if (idx < FRAME) v = *(const float4*)(&xs[fi * SX + idx]);
        w[4 * m + 0] = v.x; w[4 * m + 1] = v.y;
        w[4 * m + 2] = v.z; w[4 * m + 3] = v.w;
    }

    // ---- partial autocorrelation over 20 samples, all 17 lags ----
    float r[ORDER + 1];
#pragma unroll
    for (int k = 0; k <= ORDER; ++k) r[k] = 0.f;
#pragma unroll
    for (int n = 0; n < SEG; ++n) {
#pragma unroll
        for (int k = 0; k <= ORDER; ++k) {
            r[k] = fmaf(w[n], w[n + k], r[k]);
        }
    }
    // 8-lane butterfly: every lane of the group gets full-frame r[k]
#pragma unroll
    for (int k = 0; k <= ORDER; ++k) {
        r[k] += __shfl_xor(r[k], 1);
        r[k] += __shfl_xor(r[k], 2);
        r[k] += __shfl_xor(r[k], 4);
    }

    // ---- Levinson-Durbin (redundant across the 8 group lanes; in-place
    //      pairwise update -> no na[] temp array, ~17 fewer live VGPRs) ----
    float a[ORDER + 1];
    a[0] = 1.f;
#pragma unroll
    for (int j = 1; j <= ORDER; ++j) a[j] = 0.f;
    float e = (r[0] != 0.f) ? r[0] : LPC_EPS;  // e >= EPS > 0 afterwards
#pragma unroll
    for (int i = 1; i <= ORDER; ++i) {
        float acc = r[i];
#pragma unroll
        for (int j = 1; j < i; ++j) acc -= a[j] * r[i - j];
        float k = acc / e;
        // a_new[j] = a[j] - k*a[i-j] for j=1..i-1, done as (j, i-j) pairs:
#pragma unroll
        for (int j = 1; 2 * j < i; ++j) {
            float aj = a[j], aij = a[i - j];
            a[j]     = aj  - k * aij;
            a[i - j] = aij - k * aj;
        }
        if ((i & 1) == 0) {
            int m = i >> 1;                 // self-paired middle element
            a[m] = a[m] - k * a[m];
        }
        a[i] = k;
        e = fmaxf(e * (1.f - k * k), LPC_EPS);
    }

    // ---- FIR look-back: pre[j] = x[sbase - 16 + j], zeros before frame start ----
    float pre[ORDER];
#pragma unroll
    for (int m = 0; m < ORDER / 4; ++m) {
        int idx = sbase - ORDER + 4 * m;
        float4 v = make_float4(0.f, 0.f, 0.f, 0.f);
        if (idx >= 0) v = *(const float4*)(&xs[fi * SX + idx]);
        pre[4 * m + 0] = v.x; pre[4 * m + 1] = v.y;
        pre[4 * m + 2] = v.z; pre[4 * m + 3] = v.w;
    }

    __syncthreads();  // ALL xs reads done before in-place overwrite

    // ---- FIR: res[sbase+n] = sum_k a[k] * x[sbase+n-k], written in place ----
#pragma unroll
    for (int m = 0; m < SEG / 4; ++m) {
        float o[4];
#pragma unroll
        for (int i = 0; i < 4; ++i) {
            int n = 4 * m + i;
            float s = 0.f;
#pragma unroll
            for (int k = 0; k <= ORDER; ++k) {
                int j = n - k;                       // compile-time
                float xv = (j >= 0) ? w[j] : pre[ORDER + j];
                s = fmaf(a[k], xv, s);
            }
            o[i] = s;
        }
        *(float4*)(&xs[fi * SX + sbase + 4 * m]) = make_float4(o[0], o[1], o[2], o[3]);
    }
    __syncthreads();

    // ---- stage out: fully coalesced ----
#pragma unroll
    for (int it = 0; it < QPB; ++it) {
        int p = it * BS + t;
        int f = p / 40;
        int off = (p - f * 40) * 4;
        float4 v = *(const float4*)(&xs[f * SX + off]);
        *(float4*)(out + base + 4 * p) = v;
    }
}

extern "C" void kernel_launch(void* const* d_in, const int* in_sizes, int n_in,
                              void* d_out, int out_size, void* d_ws, size_t ws_size,
                              hipStream_t stream) {
    const float* x = (const float*)d_in[0];
    float* out = (float*)d_out;
    int total = in_sizes[0];                 // 20,480,000 = 128,000 frames
    int n_frames = total / FRAME;
    int n_blocks = n_frames / NF;            // 4000 (exact for this problem shape)
    lpc_fused<<<n_blocks, BS, 0, stream>>>(x, out);
}